// Round 7
// baseline (355.522 us; speedup 1.0000x reference)
//
#include <hip/hip_runtime.h>

typedef unsigned short u16;
typedef __bf16 bf16x8 __attribute__((ext_vector_type(8)));
typedef float f32x4 __attribute__((ext_vector_type(4)));

// fp32 -> bf16 round-to-nearest-even (finite values; no NaN path needed here)
__device__ __forceinline__ u16 f2bf(float f) {
  unsigned int u = __float_as_uint(f);
  return (u16)((u + 0x7fffu + ((u >> 16) & 1u)) >> 16);
}

// ---------------------------------------------------------------------------
// out = bf16(x) @ Wtil^T + bias, ONE uniform GEMM 2048 x 7168 x 4096, where
// Wtil folds the mean-over-perms: Wtil_i[d,g*512+f] = sum_j C_i[g,j]*W_i[d,j*512+f].
// Round 7 = round-6 READ-AHEAD schedule (validated correct) x round-4
// 16x16x32 fragment pattern (validated 0 bank conflicts). Round 6's 11M
// conflicts came from the 32x32 fragment read (32 consecutive rows per
// lane-half); the 16-row-stripe-per-quarter pattern measures 0.
// Read-ahead: phase p issues ds_reads for phase p+1's MFMA -> lgkm waits are
// no-ops and LDS service hides under MFMA. One barrier per phase.
// ---------------------------------------------------------------------------

// ---------------------------------------------------------------------------
// Kernel 1: prep (one dispatch).  [unchanged — near roofline]
// ---------------------------------------------------------------------------
__global__ __launch_bounds__(256) void k_prep(
    const float* __restrict__ x,
    const int* p0, const int* p1, const int* p2, const int* p3,
    const int* p4, const int* p5, const int* p6,
    const float* W0, const float* W1, const float* W2, const float* W3,
    const float* W4, const float* W5, const float* W6,
    u16* __restrict__ Xb16, u16* __restrict__ Wtil) {
  __shared__ float sC[64];                 // C_i[g][j], g=0..7, j=0..7
  const int bid = blockIdx.x;
  const int t = threadIdx.x;
  if (bid < 1792) {
    const int r0 = bid << 2;               // global output row (n) base
    const int i = r0 >> 10;                // scale index 0..6 (uniform/block)
    const int scale = 8 - i;
    const int K = scale << 9;              // scale*512
    const int d0 = r0 - (i << 10);
    if (t < 64) {
      const int g = t >> 3, j = t & 7;
      float v = 0.f;
      if (j < scale) {
        const int* p = (i == 0) ? p0 : (i == 1) ? p1 : (i == 2) ? p2 :
                       (i == 3) ? p3 : (i == 4) ? p4 : (i == 5) ? p5 : p6;
        int cnt = 0;
        for (int s = 0; s < 12; ++s) cnt += (p[s * scale + j] == g) ? 1 : 0;
        v = (float)cnt * (1.0f / 12.0f);
      }
      sC[t] = v;
    }
    __syncthreads();
    const float* Wi = (i == 0) ? W0 : (i == 1) ? W1 : (i == 2) ? W2 :
                      (i == 3) ? W3 : (i == 4) ? W4 : (i == 5) ? W5 : W6;
    const int u = t & 63;                  // f-octet: f = u*8 .. u*8+7
    const int gq = t >> 6;                 // wave -> g pair {2gq, 2gq+1}
    u16* dst = Wtil + ((size_t)r0 << 12);  // r0 * 4096
    for (int r = 0; r < 4; ++r) {
      const float* wrow = Wi + (size_t)(d0 + r) * K;
      float a0[8], a1[8];
#pragma unroll
      for (int e = 0; e < 8; ++e) { a0[e] = 0.f; a1[e] = 0.f; }
      for (int j = 0; j < scale; ++j) {
        const float* wp = wrow + j * 512 + (u << 3);
        const float4 wa = *reinterpret_cast<const float4*>(wp);
        const float4 wb = *reinterpret_cast<const float4*>(wp + 4);
        const float c0 = sC[(gq << 4) + j];        // C[2gq][j]
        const float c1 = sC[(gq << 4) + 8 + j];    // C[2gq+1][j]
        a0[0] += c0 * wa.x; a0[1] += c0 * wa.y; a0[2] += c0 * wa.z; a0[3] += c0 * wa.w;
        a0[4] += c0 * wb.x; a0[5] += c0 * wb.y; a0[6] += c0 * wb.z; a0[7] += c0 * wb.w;
        a1[0] += c1 * wa.x; a1[1] += c1 * wa.y; a1[2] += c1 * wa.z; a1[3] += c1 * wa.w;
        a1[4] += c1 * wb.x; a1[5] += c1 * wb.y; a1[6] += c1 * wb.z; a1[7] += c1 * wb.w;
      }
      uint4 o0, o1;
      o0.x = (unsigned)f2bf(a0[0]) | ((unsigned)f2bf(a0[1]) << 16);
      o0.y = (unsigned)f2bf(a0[2]) | ((unsigned)f2bf(a0[3]) << 16);
      o0.z = (unsigned)f2bf(a0[4]) | ((unsigned)f2bf(a0[5]) << 16);
      o0.w = (unsigned)f2bf(a0[6]) | ((unsigned)f2bf(a0[7]) << 16);
      o1.x = (unsigned)f2bf(a1[0]) | ((unsigned)f2bf(a1[1]) << 16);
      o1.y = (unsigned)f2bf(a1[2]) | ((unsigned)f2bf(a1[3]) << 16);
      o1.z = (unsigned)f2bf(a1[4]) | ((unsigned)f2bf(a1[5]) << 16);
      o1.w = (unsigned)f2bf(a1[6]) | ((unsigned)f2bf(a1[7]) << 16);
      u16* drow = dst + ((size_t)r << 12) + (gq << 10) + (u << 3);
      *reinterpret_cast<uint4*>(drow) = o0;        // g = 2gq
      *reinterpret_cast<uint4*>(drow + 512) = o1;  // g = 2gq+1
    }
  } else {
    // x cast: 2048*4096 fp32 -> bf16
    const int tid0 = ((bid - 1792) << 8) | t;
    const float4* X4 = reinterpret_cast<const float4*>(x);
    uint4* O = reinterpret_cast<uint4*>(Xb16);
#pragma unroll 4
    for (int it = 0; it < 16; ++it) {
      const int e = tid0 + (it << 16);
      const float4 a = X4[(size_t)e * 2];
      const float4 c = X4[(size_t)e * 2 + 1];
      uint4 o;
      o.x = (unsigned)f2bf(a.x) | ((unsigned)f2bf(a.y) << 16);
      o.y = (unsigned)f2bf(a.z) | ((unsigned)f2bf(a.w) << 16);
      o.z = (unsigned)f2bf(c.x) | ((unsigned)f2bf(c.y) << 16);
      o.w = (unsigned)f2bf(c.z) | ((unsigned)f2bf(c.w) << 16);
      O[e] = o;
    }
  }
}

// ---------------------------------------------------------------------------
// Kernel 2: bf16 MFMA GEMM 2048 x 7168 x 4096, 256x256 tile, 8 waves,
// 16x16x32 MFMA, global-quadrant phases with READ-AHEAD.
//   LDS 128 KB: dbuf d at d*32768 u16; A-lo +0, A-hi +8192, B-lo +16384,
//   B-hi +24576.  Phases per K-tile t: Q1=(Mlo,Nlo) Q2=(Mlo,Nhi)
//   Q3=(Mhi,Nhi) Q4=(Mhi,Nlo); 8 waves split 128x128 as 2x4 -> 64x32/wave
//   = 4 mf x 2 nf x 2 kk x 16x16x32 = 16 MFMA/phase/wave.
//   Fragment pattern (verified 0-conflict in r2/r4): 16-row stripe per
//   16-lane quarter, chunk = quad (+4 via ^32 for kk=1), rotation swizzle
//   slot = (chunk + row) & 7.
//   Read-ahead: ph1:RD bHi(t)  ph2:RD aHi(t)  ph3:RD aLo(t+1)
//   ph4:[MFMA first] RD bLo(t+1)  ph5:RD bHi(t+1) ph6:RD aHi(t+1)
//   ph7:RD aLo(t+2) ph8:[MFMA first] RD bLo(t+2).
//   Stages (1 half-tile/phase; FIFO-verified in r6 which passed refcheck):
//   S1:Blo(2j+1) S2:Ahi(2j+1) S3:Alo(2j+2) S4:Bhi(2j+2) S5:Blo(2j+2)
//   S6:Ahi(2j+2) S7:Alo(2j+3) S8:Bhi(2j+3).
//   Waits: e1:vm6 e2:vm6 e3:vm4 e4:- e5:vm6 e6:vm6 e7:vm4 e8:-.
//   ONE barrier per phase.
// ---------------------------------------------------------------------------
__device__ __forceinline__ void gl_lds16(const u16* g, u16* l) {
  __builtin_amdgcn_global_load_lds(
      (const __attribute__((address_space(1))) void*)g,
      (__attribute__((address_space(3))) void*)l, 16, 0, 0);
}

#define VM6 __builtin_amdgcn_s_waitcnt(0x0F76)
#define VM4 __builtin_amdgcn_s_waitcnt(0x0F74)
#define VM2 __builtin_amdgcn_s_waitcnt(0x0F72)
#define VM0 __builtin_amdgcn_s_waitcnt(0x0F70)
#define BAR __builtin_amdgcn_s_barrier()
#define PRIO1 __builtin_amdgcn_s_setprio(1)
#define PRIO0 __builtin_amdgcn_s_setprio(0)

// read A-half (4 mf x 2 kk) from lds base (db + 0 or db + 8192)
#define RD_A_(dst, BASE)                                                     \
  _Pragma("unroll")                                                          \
  for (int mf_ = 0; mf_ < 4; ++mf_) {                                        \
    dst[mf_][0] = *reinterpret_cast<const bf16x8*>(lds + (BASE) + offA[mf_]);        \
    dst[mf_][1] = *reinterpret_cast<const bf16x8*>(lds + (BASE) + (offA[mf_] ^ 32)); \
  }

// read B-half (2 nf x 2 kk) from lds base (db + 16384 or db + 24576)
#define RD_B_(dst, BASE)                                                     \
  _Pragma("unroll")                                                          \
  for (int nf_ = 0; nf_ < 2; ++nf_) {                                        \
    dst[nf_][0] = *reinterpret_cast<const bf16x8*>(lds + (BASE) + offB[nf_]);        \
    dst[nf_][1] = *reinterpret_cast<const bf16x8*>(lds + (BASE) + (offB[nf_] ^ 32)); \
  }

// 16 MFMA: acc[QD][mf][nf] += A[mf][kk] * B[nf][kk], 16x16x32, kk chained
#define MFMA_Q(QD, AH, BH)                                                   \
  PRIO1;                                                                     \
  _Pragma("unroll")                                                          \
  for (int mf_ = 0; mf_ < 4; ++mf_) {                                        \
    _Pragma("unroll")                                                        \
    for (int nf_ = 0; nf_ < 2; ++nf_) {                                      \
      acc[QD][mf_][nf_] = __builtin_amdgcn_mfma_f32_16x16x32_bf16(           \
          AH[mf_][0], BH[nf_][0], acc[QD][mf_][nf_], 0, 0, 0);               \
      acc[QD][mf_][nf_] = __builtin_amdgcn_mfma_f32_16x16x32_bf16(           \
          AH[mf_][1], BH[nf_][1], acc[QD][mf_][nf_], 0, 0, 0);               \
    }                                                                        \
  }                                                                          \
  PRIO0;

__global__ __launch_bounds__(512, 2) void k_gemm(
    const u16* __restrict__ A, const u16* __restrict__ Bm,
    const float* b0, const float* b1, const float* b2, const float* b3,
    const float* b4, const float* b5, const float* b6,
    float* __restrict__ out) {
  __shared__ u16 lds[65536];          // 128 KB
  const int bid = blockIdx.x;         // 224 = 8 m-tiles x 28 n-tiles
  const int blockM = (bid & 7) * 256;   // bid%8 = XCD: A-panel L2-resident
  const int blockN = (bid >> 3) * 256;

  const int tid = threadIdx.x;        // 512 threads, 8 waves
  const int lane = tid & 63;
  const int wid = tid >> 6;
  const int wm = (wid >> 2) * 64;     // row offset within 128-row quadrant
  const int wn = (wid & 3) * 32;      // col offset within 128-col quadrant
  const int quad = lane >> 4;
  const int l15 = lane & 15;

  // ---- staging addresses (2 chunks per half-tile per thread) ----
  const int srow = tid >> 3;          // 0..63
  const int sslot = tid & 7;
  const int gch = (sslot - srow) & 7; // rotation swizzle (source side)
  const u16* gA0 = A + (size_t)(blockM + srow) * 4096 + gch * 8;
  const u16* gB0 = Bm + (size_t)(blockN + srow) * 4096 + gch * 8;

  // ---- LDS read offsets (u16 units within a half; kk=1 via ^32 = chunk+4) ----
  int offA[4], offB[2];
#pragma unroll
  for (int mf = 0; mf < 4; ++mf) {
    const int r = wm + mf * 16 + l15;              // 0..127
    offA[mf] = r * 64 + ((quad + r) & 7) * 8;
  }
#pragma unroll
  for (int nf = 0; nf < 2; ++nf) {
    const int r = wn + nf * 16 + l15;              // 0..127
    offB[nf] = r * 64 + ((quad + r) & 7) * 8;
  }

  f32x4 acc[4][4][2];
#pragma unroll
  for (int q = 0; q < 4; ++q)
#pragma unroll
    for (int m = 0; m < 4; ++m)
#pragma unroll
      for (int n = 0; n < 2; ++n) {
        f32x4 z = {0.f, 0.f, 0.f, 0.f};
        acc[q][m][n] = z;
      }

  // stage one half-tile: mat 0=A 1=B, half h, K-tile t, dbuf base db (u16)
  auto stage = [&](int mat, int h, int t, int db) {
    const u16* g = (mat ? gB0 : gA0) + (size_t)h * (128 * 4096) + (size_t)t * 64;
    u16* l = lds + db + mat * 16384 + h * 8192 + (tid << 3);
    gl_lds16(g, l);
    gl_lds16(g + (size_t)(64 * 4096), l + 4096);
  };

  bf16x8 aLo[4][2], aHi[4][2], bLo[2][2], bHi[2][2];

  // ---- prologue: t0 full -> db0; t1 {Alo,Bhi} -> db1 (j=0 stages the rest).
  // vmcnt(0) retires own-wave loads; the BARRIER publishes all waves' rows;
  // reads strictly after it (round-5 lesson).
  stage(0, 0, 0, 0); stage(1, 0, 0, 0); stage(1, 1, 0, 0); stage(0, 1, 0, 0);
  stage(0, 0, 1, 32768); stage(1, 1, 1, 32768);
  VM0;
  BAR;
  RD_A_(aLo, 0)             // aLo(t0)
  RD_B_(bLo, 16384)         // bLo(t0)

  for (int j = 0; j < 31; ++j) {      // tiles t=2j, t+1; stages through 2j+3
    const int t1 = 2 * j + 1;
    const int t2 = 2 * j + 2;
    const int t3 = 2 * j + 3;

    // ph1: Q1(t); RD bHi(t); S1=Blo(t1)->db1
    RD_B_(bHi, 24576)
    stage(1, 0, t1, 32768);
    MFMA_Q(0, aLo, bLo)
    VM6; BAR;

    // ph2: Q2(t); RD aHi(t); S2=Ahi(t1)->db1
    RD_A_(aHi, 8192)
    stage(0, 1, t1, 32768);
    MFMA_Q(1, aLo, bHi)
    VM6; BAR;

    // ph3: Q3(t); RD aLo(t+1); S3=Alo(t2)->db0
    RD_A_(aLo, 32768)
    stage(0, 0, t2, 0);
    MFMA_Q(2, aHi, bHi)
    VM4; BAR;

    // ph4: Q4(t); S4=Bhi(t2)->db0; late RD bLo(t+1)
    stage(1, 1, t2, 0);
    MFMA_Q(3, aHi, bLo)
    RD_B_(bLo, 32768 + 16384)
    BAR;

    // ph5: Q1(t+1); RD bHi(t+1); S5=Blo(t2)->db0
    RD_B_(bHi, 32768 + 24576)
    stage(1, 0, t2, 0);
    MFMA_Q(0, aLo, bLo)
    VM6; BAR;

    // ph6: Q2(t+1); RD aHi(t+1); S6=Ahi(t2)->db0
    RD_A_(aHi, 32768 + 8192)
    stage(0, 1, t2, 0);
    MFMA_Q(1, aLo, bHi)
    VM6; BAR;

    // ph7: Q3(t+1); RD aLo(t+2); S7=Alo(t3)->db1
    RD_A_(aLo, 0)
    stage(0, 0, t3, 32768);
    MFMA_Q(2, aHi, bHi)
    VM4; BAR;

    // ph8: Q4(t+1); S8=Bhi(t3)->db1; late RD bLo(t+2)
    stage(1, 1, t3, 32768);
    MFMA_Q(3, aHi, bLo)
    RD_B_(bLo, 16384)
    BAR;
  }

  // ---- drain: tiles 62 (db0) / 63 (db1); only stages Blo(63), Ahi(63). ----
  {
    // dph1: Q1(62); RD bHi(62); stage Blo(63)->db1
    RD_B_(bHi, 24576)
    stage(1, 0, 63, 32768);
    MFMA_Q(0, aLo, bLo)
    VM6; BAR;

    // dph2: Q2(62); RD aHi(62); stage Ahi(63)->db1
    RD_A_(aHi, 8192)
    stage(0, 1, 63, 32768);
    MFMA_Q(1, aLo, bHi)
    VM6; BAR;

    // dph3: Q3(62); RD aLo(63)
    RD_A_(aLo, 32768)
    MFMA_Q(2, aHi, bHi)
    VM2; BAR;

    // dph4: Q4(62); late RD bLo(63)
    MFMA_Q(3, aHi, bLo)
    RD_B_(bLo, 32768 + 16384)
    BAR;

    // dph5: Q1(63); RD bHi(63)
    RD_B_(bHi, 32768 + 24576)
    MFMA_Q(0, aLo, bLo)
    VM0; BAR;

    // dph6: Q2(63); RD aHi(63)
    RD_A_(aHi, 32768 + 8192)
    MFMA_Q(1, aLo, bHi)
    BAR;

    // dph7: Q3(63)
    MFMA_Q(2, aHi, bHi)
    BAR;

    // dph8: Q4(63)
    MFMA_Q(3, aHi, bLo)
  }

  // ---- epilogue: D row = 16*mf + quad*4 + reg (in quadrant), col = 16*nf + l15
  const int isc = blockN >> 10;
  const float* bi = (isc == 0) ? b0 : (isc == 1) ? b1 : (isc == 2) ? b2 :
                    (isc == 3) ? b3 : (isc == 4) ? b4 : (isc == 5) ? b5 : b6;
#pragma unroll
  for (int qd = 0; qd < 4; ++qd) {
    const int Mq = (qd >= 2) ? 128 : 0;
    const int Nq = (qd == 1 || qd == 2) ? 128 : 0;
#pragma unroll
    for (int nf = 0; nf < 2; ++nf) {
      const int ncol = blockN + Nq + wn + nf * 16 + l15;
      const float bias = bi[ncol & 1023];
#pragma unroll
      for (int mf = 0; mf < 4; ++mf) {
        const int mbase = blockM + Mq + wm + mf * 16 + quad * 4;
#pragma unroll
        for (int reg = 0; reg < 4; ++reg)
          out[(size_t)(mbase + reg) * 7168 + ncol] = acc[qd][mf][nf][reg] + bias;
      }
    }
  }
}

// ---------------------------------------------------------------------------
extern "C" void kernel_launch(void* const* d_in, const int* in_sizes, int n_in,
                              void* d_out, int out_size, void* d_ws, size_t ws_size,
                              hipStream_t stream) {
  const float* input = (const float*)d_in[0];
  const int* perms[7];
  const float* W[7];
  const float* bias[7];
  for (int i = 0; i < 7; ++i) {
    perms[i] = (const int*)d_in[1 + 3 * i];
    W[i]     = (const float*)d_in[2 + 3 * i];
    bias[i]  = (const float*)d_in[3 + 3 * i];
  }
  char* ws = (char*)d_ws;
  u16* Xb16 = (u16*)ws;                                // 2048*4096 bf16 = 16.8 MB
  u16* Wtil = (u16*)(ws + (size_t)2048 * 4096 * 2);    // 7168*4096 bf16 = 58.7 MB

  k_prep<<<2048, 256, 0, stream>>>(input,
                                   perms[0], perms[1], perms[2], perms[3],
                                   perms[4], perms[5], perms[6],
                                   W[0], W[1], W[2], W[3], W[4], W[5], W[6],
                                   Xb16, Wtil);
  k_gemm<<<224, 512, 0, stream>>>(Xb16, Wtil,
                                  bias[0], bias[1], bias[2], bias[3],
                                  bias[4], bias[5], bias[6],
                                  (float*)d_out);
}

// Round 9
// 304.882 us; speedup vs baseline: 1.1661x; 1.1661x over previous
//
#include <hip/hip_runtime.h>

typedef unsigned short u16;
typedef __bf16 bf16x8 __attribute__((ext_vector_type(8)));
typedef float f32x4 __attribute__((ext_vector_type(4)));

// fp32 -> bf16 round-to-nearest-even (finite values; no NaN path needed here)
__device__ __forceinline__ u16 f2bf(float f) {
  unsigned int u = __float_as_uint(f);
  return (u16)((u + 0x7fffu + ((u >> 16) & 1u)) >> 16);
}

// ---------------------------------------------------------------------------
// out = bf16(x) @ Wtil^T + bias, ONE uniform GEMM 2048 x 7168 x 4096, where
// Wtil folds the mean-over-perms: Wtil_i[d,g*512+f] = sum_j C_i[g,j]*W_i[d,j*512+f].
// Round 9 = round 8 with the peel bug FIXED: tile 63's Ahi/Blo/Bhi are staged
// in ph1p/ph2p/ph3p (r8 never staged them -> K-tile 63 used stale data,
// absmax 0.257). FIFO-exact peel waits: vmcnt(4)@ph3p publishes A(63) for
// ph4p's PONG read; vmcnt(0)@ph4p publishes B(63) for ph5p/ph6p.
// Deltas vs proven r2 (123us): balanced read bursts 4/4/8/8 via PING/PONG
// A-register sets read one phase ahead, and no lgkmcnt(0) at reg-only MFMA
// phases (ph4/ph8/ph4p) so the read-ahead service hides under them.
// ---------------------------------------------------------------------------

// ---------------------------------------------------------------------------
// Kernel 1: prep (one dispatch).  [unchanged — near roofline]
// ---------------------------------------------------------------------------
__global__ __launch_bounds__(256) void k_prep(
    const float* __restrict__ x,
    const int* p0, const int* p1, const int* p2, const int* p3,
    const int* p4, const int* p5, const int* p6,
    const float* W0, const float* W1, const float* W2, const float* W3,
    const float* W4, const float* W5, const float* W6,
    u16* __restrict__ Xb16, u16* __restrict__ Wtil) {
  __shared__ float sC[64];                 // C_i[g][j], g=0..7, j=0..7
  const int bid = blockIdx.x;
  const int t = threadIdx.x;
  if (bid < 1792) {
    const int r0 = bid << 2;               // global output row (n) base
    const int i = r0 >> 10;                // scale index 0..6 (uniform/block)
    const int scale = 8 - i;
    const int K = scale << 9;              // scale*512
    const int d0 = r0 - (i << 10);
    if (t < 64) {
      const int g = t >> 3, j = t & 7;
      float v = 0.f;
      if (j < scale) {
        const int* p = (i == 0) ? p0 : (i == 1) ? p1 : (i == 2) ? p2 :
                       (i == 3) ? p3 : (i == 4) ? p4 : (i == 5) ? p5 : p6;
        int cnt = 0;
        for (int s = 0; s < 12; ++s) cnt += (p[s * scale + j] == g) ? 1 : 0;
        v = (float)cnt * (1.0f / 12.0f);
      }
      sC[t] = v;
    }
    __syncthreads();
    const float* Wi = (i == 0) ? W0 : (i == 1) ? W1 : (i == 2) ? W2 :
                      (i == 3) ? W3 : (i == 4) ? W4 : (i == 5) ? W5 : W6;
    const int u = t & 63;                  // f-octet: f = u*8 .. u*8+7
    const int gq = t >> 6;                 // wave -> g pair {2gq, 2gq+1}
    u16* dst = Wtil + ((size_t)r0 << 12);  // r0 * 4096
    for (int r = 0; r < 4; ++r) {
      const float* wrow = Wi + (size_t)(d0 + r) * K;
      float a0[8], a1[8];
#pragma unroll
      for (int e = 0; e < 8; ++e) { a0[e] = 0.f; a1[e] = 0.f; }
      for (int j = 0; j < scale; ++j) {
        const float* wp = wrow + j * 512 + (u << 3);
        const float4 wa = *reinterpret_cast<const float4*>(wp);
        const float4 wb = *reinterpret_cast<const float4*>(wp + 4);
        const float c0 = sC[(gq << 4) + j];        // C[2gq][j]
        const float c1 = sC[(gq << 4) + 8 + j];    // C[2gq+1][j]
        a0[0] += c0 * wa.x; a0[1] += c0 * wa.y; a0[2] += c0 * wa.z; a0[3] += c0 * wa.w;
        a0[4] += c0 * wb.x; a0[5] += c0 * wb.y; a0[6] += c0 * wb.z; a0[7] += c0 * wb.w;
        a1[0] += c1 * wa.x; a1[1] += c1 * wa.y; a1[2] += c1 * wa.z; a1[3] += c1 * wa.w;
        a1[4] += c1 * wb.x; a1[5] += c1 * wb.y; a1[6] += c1 * wb.z; a1[7] += c1 * wb.w;
      }
      uint4 o0, o1;
      o0.x = (unsigned)f2bf(a0[0]) | ((unsigned)f2bf(a0[1]) << 16);
      o0.y = (unsigned)f2bf(a0[2]) | ((unsigned)f2bf(a0[3]) << 16);
      o0.z = (unsigned)f2bf(a0[4]) | ((unsigned)f2bf(a0[5]) << 16);
      o0.w = (unsigned)f2bf(a0[6]) | ((unsigned)f2bf(a0[7]) << 16);
      o1.x = (unsigned)f2bf(a1[0]) | ((unsigned)f2bf(a1[1]) << 16);
      o1.y = (unsigned)f2bf(a1[2]) | ((unsigned)f2bf(a1[3]) << 16);
      o1.z = (unsigned)f2bf(a1[4]) | ((unsigned)f2bf(a1[5]) << 16);
      o1.w = (unsigned)f2bf(a1[6]) | ((unsigned)f2bf(a1[7]) << 16);
      u16* drow = dst + ((size_t)r << 12) + (gq << 10) + (u << 3);
      *reinterpret_cast<uint4*>(drow) = o0;        // g = 2gq
      *reinterpret_cast<uint4*>(drow + 512) = o1;  // g = 2gq+1
    }
  } else {
    // x cast: 2048*4096 fp32 -> bf16
    const int tid0 = ((bid - 1792) << 8) | t;
    const float4* X4 = reinterpret_cast<const float4*>(x);
    uint4* O = reinterpret_cast<uint4*>(Xb16);
#pragma unroll 4
    for (int it = 0; it < 16; ++it) {
      const int e = tid0 + (it << 16);
      const float4 a = X4[(size_t)e * 2];
      const float4 c = X4[(size_t)e * 2 + 1];
      uint4 o;
      o.x = (unsigned)f2bf(a.x) | ((unsigned)f2bf(a.y) << 16);
      o.y = (unsigned)f2bf(a.z) | ((unsigned)f2bf(a.w) << 16);
      o.z = (unsigned)f2bf(c.x) | ((unsigned)f2bf(c.y) << 16);
      o.w = (unsigned)f2bf(c.z) | ((unsigned)f2bf(c.w) << 16);
      O[e] = o;
    }
  }
}

// ---------------------------------------------------------------------------
// Kernel 2: bf16 MFMA GEMM 2048 x 7168 x 4096, 256x256 tile, 8 waves,
// 16x16x32 MFMA, r2's 8-phase schedule + balanced reads (PING/PONG).
//   LDS 128 KB: dbuf d at d*32768 u16; A (256 rows) at +0, B (256 cols) at
//   +16384. Wave wr=wid>>2 reads only its A half (wr*8192 offset); wc=wid&3
//   owns B cols (wc>>1)*128+(wc&1)*64+(0..63). acc[8][4] (128x64 per wave).
//   Phase = {RD burst; stage 1 half-tile; BAR; [lgkm0 if burst consumed
//   this phase]; setprio1; 16 MFMA; setprio0; [VM]; BAR}.
//   Reads 4/4/8/8: bL@ph1, bH@ph2, aH@ph3, next-tile A-frags (PING/PONG)
//   @ph4/ph8 — guarded by VM4@ph3/ph7 (retires Alo+Ahi of that tile; covers
//   wr=0 rows 0-63 and wr=1 rows 128-191). VM2@ph4/ph8 publishes the rest.
//   Stage order (r2-verbatim): ph1:Ahi(2j+1) ph2:Blo(2j+1) ph3:Bhi(2j+1)
//   ph4:Alo(2j+2) ph5:Ahi(2j+2) ph6:Blo(2j+2) ph7:Bhi(2j+2) ph8:Alo(2j+3).
//   Rotation swizzle slot=(chunk+row)&7 (measured 0 conflicts).
//   Peel (tiles 62,63): stages Ahi/Blo/Bhi(63) at ph1p-ph3p; VM4@ph3p,
//   VM0@ph4p; no further stages.
// ---------------------------------------------------------------------------
__device__ __forceinline__ void gl_lds16(const u16* g, u16* l) {
  __builtin_amdgcn_global_load_lds(
      (const __attribute__((address_space(1))) void*)g,
      (__attribute__((address_space(3))) void*)l, 16, 0, 0);
}

#define VM4 __builtin_amdgcn_s_waitcnt(0x0F74)
#define VM2 __builtin_amdgcn_s_waitcnt(0x0F72)
#define VM0 __builtin_amdgcn_s_waitcnt(0x0F70)
#define LG0 __builtin_amdgcn_s_waitcnt(0xC07F)
#define BAR __builtin_amdgcn_s_barrier()
#define P1  __builtin_amdgcn_s_setprio(1)
#define P0  __builtin_amdgcn_s_setprio(0)

// read 4 A-frags (+^32 pair) into dst[0..3][0..1] from half QB of buffer DB
#define RD_A4(dst, DB, QB)                                                   \
  _Pragma("unroll")                                                          \
  for (int q_ = 0; q_ < 4; ++q_) {                                           \
    dst[q_][0] = *reinterpret_cast<const bf16x8*>(lds + (DB) + offA[(QB) + q_]);         \
    dst[q_][1] = *reinterpret_cast<const bf16x8*>(lds + (DB) + (offA[(QB) + q_] ^ 32)); \
  }

// read 2 B-frags (+^32 pair) into ARR[0..1][0..1] from buffer DB, frag base FB
#define RD_B2(ARR, DB, FB)                                                   \
  _Pragma("unroll")                                                          \
  for (int n_ = 0; n_ < 2; ++n_) {                                           \
    ARR[n_][0] = *reinterpret_cast<const bf16x8*>(lds + (DB) + offB[(FB) + n_]);         \
    ARR[n_][1] = *reinterpret_cast<const bf16x8*>(lds + (DB) + (offB[(FB) + n_] ^ 32)); \
  }

// 16 MFMA: acc[MB+q][NB+n] += A[q][kk] * B[n][kk]
#define MFMA_Q(MB, NB, AV, BV)                                               \
  _Pragma("unroll")                                                          \
  for (int q_ = 0; q_ < 4; ++q_) {                                           \
    _Pragma("unroll")                                                        \
    for (int n_ = 0; n_ < 2; ++n_) {                                         \
      acc[(MB) + q_][(NB) + n_] = __builtin_amdgcn_mfma_f32_16x16x32_bf16(   \
          AV[q_][0], BV[n_][0], acc[(MB) + q_][(NB) + n_], 0, 0, 0);         \
      acc[(MB) + q_][(NB) + n_] = __builtin_amdgcn_mfma_f32_16x16x32_bf16(   \
          AV[q_][1], BV[n_][1], acc[(MB) + q_][(NB) + n_], 0, 0, 0);         \
    }                                                                        \
  }

__global__ __launch_bounds__(512, 2) void k_gemm(
    const u16* __restrict__ A, const u16* __restrict__ Bm,
    const float* b0, const float* b1, const float* b2, const float* b3,
    const float* b4, const float* b5, const float* b6,
    float* __restrict__ out) {
  __shared__ u16 lds[65536];          // 128 KB: dbuf d at d*32768
  const int bid = blockIdx.x;         // 224 = 8 m-tiles x 28 n-tiles
  const int blockM = (bid & 7) * 256;   // bid%8 = XCD: A-panel L2-resident
  const int blockN = (bid >> 3) * 256;

  const int tid = threadIdx.x;        // 512 threads, 8 waves
  const int lane = tid & 63;
  const int wid = tid >> 6;
  const int wr = wid >> 2;            // 0..1 -> A rows wr*128..
  const int wc = wid & 3;             // 0..3 -> B cols
  const int quad = lane >> 4;
  const int l15 = lane & 15;

  // ---- staging addresses (2 chunks per half-tile per thread) ----
  const int srow = tid >> 3;          // 0..63
  const int sslot = tid & 7;
  const int gch = (sslot - srow) & 7; // rotation swizzle (source side)
  const u16* gA0 = A + (size_t)(blockM + srow) * 4096 + gch * 8;
  const u16* gB0 = Bm + (size_t)(blockN + srow) * 4096 + gch * 8;

  // ---- LDS read offsets (u16 units, buffer-relative; kk=1 via ^32) ----
  int offA[8], offB[4];
#pragma unroll
  for (int q = 0; q < 8; ++q) {
    const int r = q * 16 + l15;                    // row within wave's 128
    offA[q] = wr * 8192 + r * 64 + ((quad + r) & 7) * 8;
  }
#pragma unroll
  for (int f = 0; f < 4; ++f) {
    const int r = (wc & 1) * 64 + f * 16 + l15;    // col within 128-col half
    offB[f] = 16384 + (wc >> 1) * 8192 + r * 64 + ((quad + r) & 7) * 8;
  }

  f32x4 acc[8][4];
#pragma unroll
  for (int q = 0; q < 8; ++q)
#pragma unroll
    for (int c = 0; c < 4; ++c) {
      f32x4 z = {0.f, 0.f, 0.f, 0.f};
      acc[q][c] = z;
    }

  // stage one half-tile: mat 0=A 1=B, half h, K-tile t, dbuf base db (u16)
  auto stage = [&](int mat, int h, int t, int db) {
    const u16* g = (mat ? gB0 : gA0) + (size_t)h * (128 * 4096) + (size_t)t * 64;
    u16* l = lds + db + mat * 16384 + h * 8192 + (tid << 3);
    gl_lds16(g, l);
    gl_lds16(g + (size_t)(64 * 4096), l + 4096);
  };

  bf16x8 aPI[4][2], aPO[4][2], aH[4][2], bL[2][2], bH[2][2];

  // ---- prologue: t0 full -> db0; Alo(t1) -> db1; VM2 retires t0's 8 loads;
  // BAR publishes all waves' rows; then pre-fill PING = A(t0) fragments.
  stage(0, 0, 0, 0); stage(1, 0, 0, 0); stage(1, 1, 0, 0); stage(0, 1, 0, 0);
  stage(0, 0, 1, 32768);
  VM2;
  BAR;
  RD_A4(aPI, 0, 0)

  for (int j = 0; j < 31; ++j) {      // K-tile pairs (2j,2j+1); stages to 2j+3
    const int t1 = 2 * j + 1;
    const int t2 = 2 * j + 2;
    const int t3 = 2 * j + 3;

    // ph1 (db0, tile 2j): Q1; RD bL; stage Ahi(t1)->db1
    RD_B2(bL, 0, 0)
    stage(0, 1, t1, 32768);
    BAR; LG0; P1; MFMA_Q(0, 0, aPI, bL) P0;
    BAR;

    // ph2: Q2; RD bH; stage Blo(t1)->db1
    RD_B2(bH, 0, 2)
    stage(1, 0, t1, 32768);
    BAR; LG0; P1; MFMA_Q(0, 2, aPI, bH) P0;
    BAR;

    // ph3: Q3; RD aH; stage Bhi(t1)->db1; VM4 retires Alo+Ahi(t1)
    RD_A4(aH, 0, 4)
    stage(1, 1, t1, 32768);
    BAR; LG0; P1; MFMA_Q(4, 2, aH, bH) P0;
    VM4; BAR;

    // ph4: Q4 [reg-only MFMA, no LG0]; RD PONG = A-frags(t1)@db1
    //      (published by ph3 VM4+BAR; consumed ph5, drained by ph5 LG0);
    //      stage Alo(t2)->db0; VM2 publishes Blo/Bhi(t1)
    RD_A4(aPO, 32768, 0)
    stage(0, 0, t2, 0);
    BAR; P1; MFMA_Q(4, 0, aH, bL) P0;
    VM2; BAR;

    // ph5 (db1, tile 2j+1): Q1; RD bL; stage Ahi(t2)->db0
    RD_B2(bL, 32768, 0)
    stage(0, 1, t2, 0);
    BAR; LG0; P1; MFMA_Q(0, 0, aPO, bL) P0;
    BAR;

    // ph6: Q2; RD bH; stage Blo(t2)->db0
    RD_B2(bH, 32768, 2)
    stage(1, 0, t2, 0);
    BAR; LG0; P1; MFMA_Q(0, 2, aPO, bH) P0;
    BAR;

    // ph7: Q3; RD aH; stage Bhi(t2)->db0; VM4 retires Alo+Ahi(t2)
    RD_A4(aH, 32768, 4)
    stage(1, 1, t2, 0);
    BAR; LG0; P1; MFMA_Q(4, 2, aH, bH) P0;
    VM4; BAR;

    // ph8: Q4 [reg-only, no LG0]; RD PING = A-frags(t2)@db0;
    //      stage Alo(t3)->db1; VM2 publishes Blo/Bhi(t2)
    RD_A4(aPI, 0, 0)
    stage(0, 0, t3, 32768);
    BAR; P1; MFMA_Q(4, 0, aH, bL) P0;
    VM2; BAR;
  }

  // ---- peeled final pair: tiles 62 (db0, PING pre-filled) / 63 (db1).
  // Entering: outstanding = [Alo(63)] (2 loads, issued ph8@j=30).
  // Stages tile 63's remaining halves here (r8 BUG: these were missing).
  {
    // ph1p: Q1(62); RD bL; stage Ahi(63)->db1  [outstanding -> 4]
    RD_B2(bL, 0, 0)
    stage(0, 1, 63, 32768);
    BAR; LG0; P1; MFMA_Q(0, 0, aPI, bL) P0;
    BAR;
    // ph2p: Q2(62); RD bH; stage Blo(63)->db1  [-> 6]
    RD_B2(bH, 0, 2)
    stage(1, 0, 63, 32768);
    BAR; LG0; P1; MFMA_Q(0, 2, aPI, bH) P0;
    BAR;
    // ph3p: Q3(62); RD aH; stage Bhi(63)->db1  [-> 8]; VM4 retires
    //        Alo(63)+Ahi(63) -> publishes ph4p's A-frag read
    RD_A4(aH, 0, 4)
    stage(1, 1, 63, 32768);
    BAR; LG0; P1; MFMA_Q(4, 2, aH, bH) P0;
    VM4; BAR;
    // ph4p: Q4(62) [reg-only]; RD PONG = A-frags(63)@db1; VM0 retires
    //        Blo(63)+Bhi(63) -> publishes ph5p/ph6p B reads
    RD_A4(aPO, 32768, 0)
    BAR; P1; MFMA_Q(4, 0, aH, bL) P0;
    VM0; BAR;
    // ph5p: Q1(63)
    RD_B2(bL, 32768, 0)
    BAR; LG0; P1; MFMA_Q(0, 0, aPO, bL) P0;
    BAR;
    // ph6p: Q2(63)
    RD_B2(bH, 32768, 2)
    BAR; LG0; P1; MFMA_Q(0, 2, aPO, bH) P0;
    BAR;
    // ph7p: Q3(63)
    RD_A4(aH, 32768, 4)
    BAR; LG0; P1; MFMA_Q(4, 2, aH, bH) P0;
    BAR;
    // ph8p: Q4(63) [regs only]
    P1; MFMA_Q(4, 0, aH, bL) P0;
  }

  // ---- epilogue: D row = 16*q + quad*4 + reg, col = 16*f + l15 ----
  const int isc = blockN >> 10;
  const float* bi = (isc == 0) ? b0 : (isc == 1) ? b1 : (isc == 2) ? b2 :
                    (isc == 3) ? b3 : (isc == 4) ? b4 : (isc == 5) ? b5 : b6;
#pragma unroll
  for (int f = 0; f < 4; ++f) {
    const int ncol = blockN + (wc >> 1) * 128 + (wc & 1) * 64 + f * 16 + l15;
    const float bias = bi[ncol & 1023];
#pragma unroll
    for (int q = 0; q < 8; ++q) {
      const int mbase = blockM + wr * 128 + q * 16 + quad * 4;
#pragma unroll
      for (int reg = 0; reg < 4; ++reg)
        out[(size_t)(mbase + reg) * 7168 + ncol] = acc[q][f][reg] + bias;
    }
  }
}

// ---------------------------------------------------------------------------
extern "C" void kernel_launch(void* const* d_in, const int* in_sizes, int n_in,
                              void* d_out, int out_size, void* d_ws, size_t ws_size,
                              hipStream_t stream) {
  const float* input = (const float*)d_in[0];
  const int* perms[7];
  const float* W[7];
  const float* bias[7];
  for (int i = 0; i < 7; ++i) {
    perms[i] = (const int*)d_in[1 + 3 * i];
    W[i]     = (const float*)d_in[2 + 3 * i];
    bias[i]  = (const float*)d_in[3 + 3 * i];
  }
  char* ws = (char*)d_ws;
  u16* Xb16 = (u16*)ws;                                // 2048*4096 bf16 = 16.8 MB
  u16* Wtil = (u16*)(ws + (size_t)2048 * 4096 * 2);    // 7168*4096 bf16 = 58.7 MB

  k_prep<<<2048, 256, 0, stream>>>(input,
                                   perms[0], perms[1], perms[2], perms[3],
                                   perms[4], perms[5], perms[6],
                                   W[0], W[1], W[2], W[3], W[4], W[5], W[6],
                                   Xb16, Wtil);
  k_gemm<<<224, 512, 0, stream>>>(Xb16, Wtil,
                                  bias[0], bias[1], bias[2], bias[3],
                                  bias[4], bias[5], bias[6],
                                  (float*)d_out);
}